// Round 5
// baseline (93.827 us; speedup 1.0000x reference)
//
#include <hip/hip_runtime.h>
#include <math.h>

#define DEN_EPS_F 1e-10f

__device__ __forceinline__ float safe_rcp(float d) {
    float dc = (fabsf(d) < 1e-12f) ? 1e-12f : d;
    return __builtin_amdgcn_rcpf(dc);   // v_rcp_f32
}

// Fraction of segment {start p, direction d} inside |x|<=hx, |y|<=hy,
// given rd = 1/d componentwise. Shallow tree: lo/hi per axis -> max3/min3.
__device__ __forceinline__ float clip_dt(float px_, float py_,
                                         float rdx, float rdy,
                                         float hx, float hy) {
    float tax = (-hx - px_) * rdx, tbx = (hx - px_) * rdx;
    float tay = (-hy - py_) * rdy, tby = (hy - py_) * rdy;
    float lox = fminf(tax, tbx), hix = fmaxf(tax, tbx);
    float loy = fminf(tay, tby), hiy = fmaxf(tay, tby);
    float t0 = fmaxf(fmaxf(lox, loy), 0.0f);   // v_max3_f32
    float t1 = fminf(fminf(hix, hiy), 1.0f);   // v_min3_f32
    return fmaxf(t1 - t0, 0.0f);
}

// IoU loss for one (pred, target) pair, computed entirely in pred's local
// frame (area is rigid-motion invariant). Boundary integral identity:
// each edge's clipped cross contribution = (t1-t0)*cross(corner, dir);
// for P edges cross(p_k, r_k) = 2*hw1*hh1 (all k), for Q edges it is
// (+-Ku + W2), (+-Kv + W2). Exact rearrangement of the R4 algorithm.
__device__ __forceinline__ float box_pair_loss(const float* bp, const float* bt) {
    float x1 = bp[0], y1 = bp[1], w1 = bp[2], h1 = bp[3], ang1 = bp[4];
    float x2 = bt[0], y2 = bt[1], w2 = bt[2], h2 = bt[3], ang2 = bt[4];
    float s1, c1, sd, cd;
    __sincosf(ang1, &s1, &c1);
    __sincosf(ang2 - ang1, &sd, &cd);   // relative angle

    float hw1 = 0.5f * w1, hh1 = 0.5f * h1;
    float hw2 = 0.5f * w2, hh2 = 0.5f * h2;

    // Q center in P frame
    float tx = x2 - x1, ty = y2 - y1;
    float cx = tx * c1 + ty * s1;
    float cy = -tx * s1 + ty * c1;

    // Q half-axes in P frame
    float ux = hw2 * cd, uy = hw2 * sd;
    float vx = -hh2 * sd, vy = hh2 * cd;

    // Q corners in P frame (CCW: -u-v, +u-v, +u+v, -u+v)
    float e0x = cx - ux, e1x = cx + ux;
    float qx0 = e0x - vx, qx1 = e1x - vx, qx2 = e1x + vx, qx3 = e0x + vx;
    float e0y = cy - uy, e1y = cy + uy;
    float qy0 = e0y - vy, qy1 = e1y - vy, qy2 = e1y + vy, qy3 = e0y + vy;

    // P corners in Q frame: p_inQ = sx*A + sy*B - g,
    // A = Rd^T(hw1,0), B = Rd^T(0,hh1), g = Rd^T c
    float Axx = hw1 * cd, Axy = -hw1 * sd;
    float Bxx = hh1 * sd, Byy = hh1 * cd;
    float gx = cx * cd + cy * sd;
    float gy = -cx * sd + cy * cd;
    float f0x = -Axx - gx, f1x = Axx - gx;
    float px0 = f0x - Bxx, px1 = f1x - Bxx, px2 = f1x + Bxx, px3 = f0x + Bxx;
    float f0y = -Axy - gy, f1y = Axy - gy;
    float py0 = f0y - Byy, py1 = f1y - Byy, py2 = f1y + Byy, py3 = f0y + Byy;

    // P edges clipped in Q frame; dirs +2A, +2B, -2A, -2B (rcp shared)
    float rAx = 0.5f * safe_rcp(Axx), rAy = 0.5f * safe_rcp(Axy);
    float rBx = 0.5f * safe_rcp(Bxx), rBy = 0.5f * safe_rcp(Byy);
    float dtP = clip_dt(px0, py0, rAx, rAy, hw2, hh2)
              + clip_dt(px1, py1, rBx, rBy, hw2, hh2)
              + clip_dt(px2, py2, -rAx, -rAy, hw2, hh2)
              + clip_dt(px3, py3, -rBx, -rBy, hw2, hh2);

    // Q edges clipped in P frame (P box IS the AABB); dirs +2u,+2v,-2u,-2v
    float rux = 0.5f * safe_rcp(ux), ruy = 0.5f * safe_rcp(uy);
    float rvx = 0.5f * safe_rcp(vx), rvy = 0.5f * safe_rcp(vy);
    float dq0 = clip_dt(qx0, qy0, rux, ruy, hw1, hh1);
    float dq1 = clip_dt(qx1, qy1, rvx, rvy, hw1, hh1);
    float dq2 = clip_dt(qx2, qy2, -rux, -ruy, hw1, hh1);
    float dq3 = clip_dt(qx3, qy3, -rvx, -rvy, hw1, hh1);
    float dtQ = (dq0 + dq2) + (dq1 + dq3);

    float Ku = 2.0f * (cx * uy - cy * ux);
    float Kv = 2.0f * (cx * vy - cy * vx);
    float A1 = w1 * h1, A2 = w2 * h2;
    float acc = 0.5f * (A1 * dtP + A2 * dtQ)
              + Ku * (dq0 - dq2) + Kv * (dq1 - dq3);
    float area = 0.5f * fabsf(acc);

    float uni = fmaxf((A1 + A2) - area, DEN_EPS_F);
    float iou = area * __builtin_amdgcn_rcpf(uni);
    return -__logf(fmaxf(iou, 1e-6f));
}

#define BOX_PER_THREAD 4

__global__ __launch_bounds__(64, 4) void riou_loss_kernel(
        const float* __restrict__ pred, const float* __restrict__ target,
        float* __restrict__ out, int n, float inv_n) {
    int t = blockIdx.x * blockDim.x + threadIdx.x;
    int base = t * BOX_PER_THREAD;
    float loss = 0.0f;

    if (base + BOX_PER_THREAD - 1 < n) {
        // 4 boxes x 5 floats = 5 x float4 at byte offset t*80 (16B aligned)
        const float4* p4 = reinterpret_cast<const float4*>(pred) + (size_t)t * 5;
        const float4* t4 = reinterpret_cast<const float4*>(target) + (size_t)t * 5;
        float fp[20], ft[20];
#pragma unroll
        for (int k = 0; k < 5; ++k) {
            float4 v = p4[k];
            fp[4 * k + 0] = v.x; fp[4 * k + 1] = v.y;
            fp[4 * k + 2] = v.z; fp[4 * k + 3] = v.w;
            float4 u = t4[k];
            ft[4 * k + 0] = u.x; ft[4 * k + 1] = u.y;
            ft[4 * k + 2] = u.z; ft[4 * k + 3] = u.w;
        }
#pragma unroll
        for (int b = 0; b < BOX_PER_THREAD; ++b)
            loss += box_pair_loss(fp + 5 * b, ft + 5 * b);
    } else if (base < n) {
        // ragged tail (never taken when n % 4 == 0)
        for (int b = 0; b < BOX_PER_THREAD; ++b) {
            int idx = base + b;
            if (idx < n)
                loss += box_pair_loss(pred + (size_t)idx * 5,
                                      target + (size_t)idx * 5);
        }
    }

    // single-wave block: shuffle reduce, one atomic per block
#pragma unroll
    for (int off = 32; off > 0; off >>= 1)
        loss += __shfl_down(loss, off, 64);
    if (threadIdx.x == 0)
        atomicAdd(out, loss * inv_n);
}

extern "C" void kernel_launch(void* const* d_in, const int* in_sizes, int n_in,
                              void* d_out, int out_size, void* d_ws, size_t ws_size,
                              hipStream_t stream) {
    const float* pred = (const float*)d_in[0];
    const float* target = (const float*)d_in[1];
    float* out = (float*)d_out;
    int n = in_sizes[0] / 5;

    // d_out is re-poisoned (0xAA) before every timed replay; zero it.
    hipMemsetAsync(out, 0, sizeof(float), stream);

    int threads_needed = (n + BOX_PER_THREAD - 1) / BOX_PER_THREAD;
    int block = 64;
    int grid = (threads_needed + block - 1) / block;
    riou_loss_kernel<<<grid, block, 0, stream>>>(pred, target, out, n,
                                                 1.0f / (float)n);
}

// Round 7
// 76.332 us; speedup vs baseline: 1.2292x; 1.2292x over previous
//
#include <hip/hip_runtime.h>
#include <math.h>

#define DEN_EPS_F 1e-10f

__device__ __forceinline__ float safe_rcp(float d) {
    float dc = (fabsf(d) < 1e-12f) ? 1e-12f : d;
    return __builtin_amdgcn_rcpf(dc);   // v_rcp_f32
}

// Fraction of segment {start p, direction d} inside |x|<=hx, |y|<=hy,
// given rd = 1/d componentwise. Shallow tree: lo/hi per axis -> max3/min3.
__device__ __forceinline__ float clip_dt(float px_, float py_,
                                         float rdx, float rdy,
                                         float hx, float hy) {
    float tax = (-hx - px_) * rdx, tbx = (hx - px_) * rdx;
    float tay = (-hy - py_) * rdy, tby = (hy - py_) * rdy;
    float lox = fminf(tax, tbx), hix = fmaxf(tax, tbx);
    float loy = fminf(tay, tby), hiy = fmaxf(tay, tby);
    float t0 = fmaxf(fmaxf(lox, loy), 0.0f);   // v_max3_f32
    float t1 = fminf(fminf(hix, hiy), 1.0f);   // v_min3_f32
    return fmaxf(t1 - t0, 0.0f);
}

// IoU loss for one (pred, target) pair, computed entirely in pred's local
// frame (area is rigid-motion invariant). Boundary integral identity:
// each edge's clipped cross contribution = (t1-t0)*cross(corner, dir);
// for P edges cross(p_k, r_k) = 2*hw1*hh1 (all k), for Q edges it is
// (+-Ku + W2), (+-Kv + W2). Exact rearrangement of the R4 algorithm
// (validated absmax 0.0 in R5).
__device__ __forceinline__ float box_pair_loss(const float* bp, const float* bt) {
    float x1 = bp[0], y1 = bp[1], w1 = bp[2], h1 = bp[3], ang1 = bp[4];
    float x2 = bt[0], y2 = bt[1], w2 = bt[2], h2 = bt[3], ang2 = bt[4];
    float s1, c1, sd, cd;
    __sincosf(ang1, &s1, &c1);
    __sincosf(ang2 - ang1, &sd, &cd);   // relative angle

    float hw1 = 0.5f * w1, hh1 = 0.5f * h1;
    float hw2 = 0.5f * w2, hh2 = 0.5f * h2;

    // Q center in P frame
    float tx = x2 - x1, ty = y2 - y1;
    float cx = tx * c1 + ty * s1;
    float cy = -tx * s1 + ty * c1;

    // Q half-axes in P frame
    float ux = hw2 * cd, uy = hw2 * sd;
    float vx = -hh2 * sd, vy = hh2 * cd;

    // Q corners in P frame (CCW: -u-v, +u-v, +u+v, -u+v)
    float e0x = cx - ux, e1x = cx + ux;
    float qx0 = e0x - vx, qx1 = e1x - vx, qx2 = e1x + vx, qx3 = e0x + vx;
    float e0y = cy - uy, e1y = cy + uy;
    float qy0 = e0y - vy, qy1 = e1y - vy, qy2 = e1y + vy, qy3 = e0y + vy;

    // P corners in Q frame: p_inQ = sx*A + sy*B - g,
    // A = Rd^T(hw1,0), B = Rd^T(0,hh1), g = Rd^T c
    float Axx = hw1 * cd, Axy = -hw1 * sd;
    float Bxx = hh1 * sd, Byy = hh1 * cd;
    float gx = cx * cd + cy * sd;
    float gy = -cx * sd + cy * cd;
    float f0x = -Axx - gx, f1x = Axx - gx;
    float px0 = f0x - Bxx, px1 = f1x - Bxx, px2 = f1x + Bxx, px3 = f0x + Bxx;
    float f0y = -Axy - gy, f1y = Axy - gy;
    float py0 = f0y - Byy, py1 = f1y - Byy, py2 = f1y + Byy, py3 = f0y + Byy;

    // P edges clipped in Q frame; dirs +2A, +2B, -2A, -2B (rcp shared)
    float rAx = 0.5f * safe_rcp(Axx), rAy = 0.5f * safe_rcp(Axy);
    float rBx = 0.5f * safe_rcp(Bxx), rBy = 0.5f * safe_rcp(Byy);
    float dtP = clip_dt(px0, py0, rAx, rAy, hw2, hh2)
              + clip_dt(px1, py1, rBx, rBy, hw2, hh2)
              + clip_dt(px2, py2, -rAx, -rAy, hw2, hh2)
              + clip_dt(px3, py3, -rBx, -rBy, hw2, hh2);

    // Q edges clipped in P frame (P box IS the AABB); dirs +2u,+2v,-2u,-2v
    float rux = 0.5f * safe_rcp(ux), ruy = 0.5f * safe_rcp(uy);
    float rvx = 0.5f * safe_rcp(vx), rvy = 0.5f * safe_rcp(vy);
    float dq0 = clip_dt(qx0, qy0, rux, ruy, hw1, hh1);
    float dq1 = clip_dt(qx1, qy1, rvx, rvy, hw1, hh1);
    float dq2 = clip_dt(qx2, qy2, -rux, -ruy, hw1, hh1);
    float dq3 = clip_dt(qx3, qy3, -rvx, -rvy, hw1, hh1);
    float dtQ = (dq0 + dq2) + (dq1 + dq3);

    float Ku = 2.0f * (cx * uy - cy * ux);
    float Kv = 2.0f * (cx * vy - cy * vx);
    float A1 = w1 * h1, A2 = w2 * h2;
    float acc = 0.5f * (A1 * dtP + A2 * dtQ)
              + Ku * (dq0 - dq2) + Kv * (dq1 - dq3);
    float area = 0.5f * fabsf(acc);

    float uni = fmaxf((A1 + A2) - area, DEN_EPS_F);
    float iou = area * __builtin_amdgcn_rcpf(uni);
    return -__logf(fmaxf(iou, 1e-6f));
}

#define BOX_PER_THREAD 4

__global__ __launch_bounds__(256, 2) void riou_loss_kernel(
        const float* __restrict__ pred, const float* __restrict__ target,
        float* __restrict__ out, int n, float inv_n) {
    int t = blockIdx.x * blockDim.x + threadIdx.x;
    int base = t * BOX_PER_THREAD;
    float loss = 0.0f;

    if (base + BOX_PER_THREAD - 1 < n) {
        // 4 boxes x 5 floats = 5 x float4 at byte offset t*80 (16B aligned)
        const float4* p4 = reinterpret_cast<const float4*>(pred) + (size_t)t * 5;
        const float4* t4 = reinterpret_cast<const float4*>(target) + (size_t)t * 5;
        float fp[20], ft[20];
#pragma unroll
        for (int k = 0; k < 5; ++k) {
            float4 v = p4[k];
            fp[4 * k + 0] = v.x; fp[4 * k + 1] = v.y;
            fp[4 * k + 2] = v.z; fp[4 * k + 3] = v.w;
            float4 u = t4[k];
            ft[4 * k + 0] = u.x; ft[4 * k + 1] = u.y;
            ft[4 * k + 2] = u.z; ft[4 * k + 3] = u.w;
        }
#pragma unroll
        for (int b = 0; b < BOX_PER_THREAD; ++b)
            loss += box_pair_loss(fp + 5 * b, ft + 5 * b);
    } else if (base < n) {
        // ragged tail (never taken when n % 4 == 0)
        for (int b = 0; b < BOX_PER_THREAD; ++b) {
            int idx = base + b;
            if (idx < n)
                loss += box_pair_loss(pred + (size_t)idx * 5,
                                      target + (size_t)idx * 5);
        }
    }

    // wave (64-lane) reduction -> LDS across 4 waves -> 1 atomic/block
#pragma unroll
    for (int off = 32; off > 0; off >>= 1)
        loss += __shfl_down(loss, off, 64);

    __shared__ float wsum[4];
    int lane = threadIdx.x & 63;
    int wid = threadIdx.x >> 6;
    if (lane == 0) wsum[wid] = loss;
    __syncthreads();
    if (threadIdx.x == 0) {
        float s = (wsum[0] + wsum[1]) + (wsum[2] + wsum[3]);
        atomicAdd(out, s * inv_n);
    }
}

extern "C" void kernel_launch(void* const* d_in, const int* in_sizes, int n_in,
                              void* d_out, int out_size, void* d_ws, size_t ws_size,
                              hipStream_t stream) {
    const float* pred = (const float*)d_in[0];
    const float* target = (const float*)d_in[1];
    float* out = (float*)d_out;
    int n = in_sizes[0] / 5;

    // d_out is re-poisoned (0xAA) before every timed replay; zero it.
    hipMemsetAsync(out, 0, sizeof(float), stream);

    int threads_needed = (n + BOX_PER_THREAD - 1) / BOX_PER_THREAD;
    int block = 256;
    int grid = (threads_needed + block - 1) / block;
    riou_loss_kernel<<<grid, block, 0, stream>>>(pred, target, out, n,
                                                 1.0f / (float)n);
}

// Round 8
// 74.848 us; speedup vs baseline: 1.2536x; 1.0198x over previous
//
#include <hip/hip_runtime.h>
#include <math.h>

#define DEN_EPS_F 1e-10f

__device__ __forceinline__ float safe_rcp(float d) {
    float dc = (fabsf(d) < 1e-12f) ? 1e-12f : d;
    return __builtin_amdgcn_rcpf(dc);   // v_rcp_f32
}

// Fraction of segment {start p, direction d} inside |x|<=hx, |y|<=hy,
// given rd = 1/d componentwise. Shallow tree: lo/hi per axis -> max3/min3.
__device__ __forceinline__ float clip_dt(float px_, float py_,
                                         float rdx, float rdy,
                                         float hx, float hy) {
    float tax = (-hx - px_) * rdx, tbx = (hx - px_) * rdx;
    float tay = (-hy - py_) * rdy, tby = (hy - py_) * rdy;
    float lox = fminf(tax, tbx), hix = fmaxf(tax, tbx);
    float loy = fminf(tay, tby), hiy = fmaxf(tay, tby);
    float t0 = fmaxf(fmaxf(lox, loy), 0.0f);   // v_max3_f32
    float t1 = fminf(fminf(hix, hiy), 1.0f);   // v_min3_f32
    return fmaxf(t1 - t0, 0.0f);
}

// IoU loss for one (pred, target) pair in pred's local frame.
// Boundary-integral identity (validated absmax 0.0 in R5/R7).
__device__ __forceinline__ float box_pair_loss(const float* bp, const float* bt) {
    float x1 = bp[0], y1 = bp[1], w1 = bp[2], h1 = bp[3], ang1 = bp[4];
    float x2 = bt[0], y2 = bt[1], w2 = bt[2], h2 = bt[3], ang2 = bt[4];
    float s1, c1, sd, cd;
    __sincosf(ang1, &s1, &c1);
    __sincosf(ang2 - ang1, &sd, &cd);   // relative angle

    float hw1 = 0.5f * w1, hh1 = 0.5f * h1;
    float hw2 = 0.5f * w2, hh2 = 0.5f * h2;

    // Q center in P frame
    float tx = x2 - x1, ty = y2 - y1;
    float cx = tx * c1 + ty * s1;
    float cy = -tx * s1 + ty * c1;

    // Q half-axes in P frame
    float ux = hw2 * cd, uy = hw2 * sd;
    float vx = -hh2 * sd, vy = hh2 * cd;

    // Q corners in P frame (CCW)
    float e0x = cx - ux, e1x = cx + ux;
    float qx0 = e0x - vx, qx1 = e1x - vx, qx2 = e1x + vx, qx3 = e0x + vx;
    float e0y = cy - uy, e1y = cy + uy;
    float qy0 = e0y - vy, qy1 = e1y - vy, qy2 = e1y + vy, qy3 = e0y + vy;

    // P corners in Q frame
    float Axx = hw1 * cd, Axy = -hw1 * sd;
    float Bxx = hh1 * sd, Byy = hh1 * cd;
    float gx = cx * cd + cy * sd;
    float gy = -cx * sd + cy * cd;
    float f0x = -Axx - gx, f1x = Axx - gx;
    float px0 = f0x - Bxx, px1 = f1x - Bxx, px2 = f1x + Bxx, px3 = f0x + Bxx;
    float f0y = -Axy - gy, f1y = Axy - gy;
    float py0 = f0y - Byy, py1 = f1y - Byy, py2 = f1y + Byy, py3 = f0y + Byy;

    // P edges clipped in Q frame; dirs +-2A, +-2B (rcp shared)
    float rAx = 0.5f * safe_rcp(Axx), rAy = 0.5f * safe_rcp(Axy);
    float rBx = 0.5f * safe_rcp(Bxx), rBy = 0.5f * safe_rcp(Byy);
    float dtP = clip_dt(px0, py0, rAx, rAy, hw2, hh2)
              + clip_dt(px1, py1, rBx, rBy, hw2, hh2)
              + clip_dt(px2, py2, -rAx, -rAy, hw2, hh2)
              + clip_dt(px3, py3, -rBx, -rBy, hw2, hh2);

    // Q edges clipped in P frame (P box IS the AABB)
    float rux = 0.5f * safe_rcp(ux), ruy = 0.5f * safe_rcp(uy);
    float rvx = 0.5f * safe_rcp(vx), rvy = 0.5f * safe_rcp(vy);
    float dq0 = clip_dt(qx0, qy0, rux, ruy, hw1, hh1);
    float dq1 = clip_dt(qx1, qy1, rvx, rvy, hw1, hh1);
    float dq2 = clip_dt(qx2, qy2, -rux, -ruy, hw1, hh1);
    float dq3 = clip_dt(qx3, qy3, -rvx, -rvy, hw1, hh1);
    float dtQ = (dq0 + dq2) + (dq1 + dq3);

    float Ku = 2.0f * (cx * uy - cy * ux);
    float Kv = 2.0f * (cx * vy - cy * vx);
    float A1 = w1 * h1, A2 = w2 * h2;
    float acc = 0.5f * (A1 * dtP + A2 * dtQ)
              + Ku * (dq0 - dq2) + Kv * (dq1 - dq3);
    float area = 0.5f * fabsf(acc);

    float uni = fmaxf((A1 + A2) - area, DEN_EPS_F);
    float iou = area * __builtin_amdgcn_rcpf(uni);
    return -__logf(fmaxf(iou, 1e-6f));
}

#define BOX_PER_THREAD 2
#define NSLOT 64

__global__ __launch_bounds__(256, 2) void riou_loss_kernel(
        const float* __restrict__ pred, const float* __restrict__ target,
        float* __restrict__ slots, int n) {
    int t = blockIdx.x * blockDim.x + threadIdx.x;
    int base = t * BOX_PER_THREAD;
    float loss = 0.0f;

    if (base + BOX_PER_THREAD - 1 < n) {
        // 2 boxes x 5 floats = 5 x float2 at byte offset t*40 (8B aligned)
        const float2* p2 = reinterpret_cast<const float2*>(pred) + (size_t)t * 5;
        const float2* t2 = reinterpret_cast<const float2*>(target) + (size_t)t * 5;
        float fp[10], ft[10];
#pragma unroll
        for (int k = 0; k < 5; ++k) {
            float2 v = p2[k];
            fp[2 * k + 0] = v.x; fp[2 * k + 1] = v.y;
            float2 u = t2[k];
            ft[2 * k + 0] = u.x; ft[2 * k + 1] = u.y;
        }
#pragma unroll
        for (int b = 0; b < BOX_PER_THREAD; ++b)
            loss += box_pair_loss(fp + 5 * b, ft + 5 * b);
    } else if (base < n) {
        // ragged tail (never taken when n % 2 == 0)
        for (int b = 0; b < BOX_PER_THREAD; ++b) {
            int idx = base + b;
            if (idx < n)
                loss += box_pair_loss(pred + (size_t)idx * 5,
                                      target + (size_t)idx * 5);
        }
    }

    // wave (64-lane) reduction -> LDS across 4 waves -> 1 atomic per block
    // into one of 64 spread slots (avoids same-address serialization).
#pragma unroll
    for (int off = 32; off > 0; off >>= 1)
        loss += __shfl_down(loss, off, 64);

    __shared__ float wsum[4];
    int lane = threadIdx.x & 63;
    int wid = threadIdx.x >> 6;
    if (lane == 0) wsum[wid] = loss;
    __syncthreads();
    if (threadIdx.x == 0) {
        float s = (wsum[0] + wsum[1]) + (wsum[2] + wsum[3]);
        atomicAdd(slots + (blockIdx.x & (NSLOT - 1)), s);
    }
}

__global__ __launch_bounds__(64) void riou_finish_kernel(
        const float* __restrict__ slots, float* __restrict__ out, float inv_n) {
    float v = slots[threadIdx.x];
#pragma unroll
    for (int off = 32; off > 0; off >>= 1)
        v += __shfl_down(v, off, 64);
    if (threadIdx.x == 0)
        out[0] = v * inv_n;
}

extern "C" void kernel_launch(void* const* d_in, const int* in_sizes, int n_in,
                              void* d_out, int out_size, void* d_ws, size_t ws_size,
                              hipStream_t stream) {
    const float* pred = (const float*)d_in[0];
    const float* target = (const float*)d_in[1];
    float* out = (float*)d_out;
    float* slots = (float*)d_ws;
    int n = in_sizes[0] / 5;

    // d_ws is re-poisoned (0xAA) before every timed replay; zero the slots.
    hipMemsetAsync(slots, 0, NSLOT * sizeof(float), stream);

    int threads_needed = (n + BOX_PER_THREAD - 1) / BOX_PER_THREAD;
    int block = 256;
    int grid = (threads_needed + block - 1) / block;
    riou_loss_kernel<<<grid, block, 0, stream>>>(pred, target, slots, n);
    riou_finish_kernel<<<1, 64, 0, stream>>>(slots, out, 1.0f / (float)n);
}

// Round 9
// 71.569 us; speedup vs baseline: 1.3110x; 1.0458x over previous
//
#include <hip/hip_runtime.h>
#include <math.h>

#define DEN_EPS_F 1e-10f

__device__ __forceinline__ float safe_rcp(float d) {
    float dc = (fabsf(d) < 1e-12f) ? 1e-12f : d;
    return __builtin_amdgcn_rcpf(dc);   // v_rcp_f32
}

// Fraction of segment {start p, direction d} inside |x|<=hx, |y|<=hy,
// given rd = 1/d componentwise. Shallow tree: lo/hi per axis -> max3/min3.
__device__ __forceinline__ float clip_dt(float px_, float py_,
                                         float rdx, float rdy,
                                         float hx, float hy) {
    float tax = (-hx - px_) * rdx, tbx = (hx - px_) * rdx;
    float tay = (-hy - py_) * rdy, tby = (hy - py_) * rdy;
    float lox = fminf(tax, tbx), hix = fmaxf(tax, tbx);
    float loy = fminf(tay, tby), hiy = fmaxf(tay, tby);
    float t0 = fmaxf(fmaxf(lox, loy), 0.0f);   // v_max3_f32
    float t1 = fminf(fminf(hix, hiy), 1.0f);   // v_min3_f32
    return fmaxf(t1 - t0, 0.0f);
}

// IoU loss for one (pred, target) pair in pred's local frame.
// ALL parameters by value -> no addressable locals -> guaranteed VGPRs.
// Boundary-integral identity (validated absmax 0.0 in R5/R7/R8).
__device__ __forceinline__ float box_pair_loss(
        float x1, float y1, float w1, float h1, float ang1,
        float x2, float y2, float w2, float h2, float ang2) {
    float s1, c1, sd, cd;
    __sincosf(ang1, &s1, &c1);
    __sincosf(ang2 - ang1, &sd, &cd);   // relative angle

    float hw1 = 0.5f * w1, hh1 = 0.5f * h1;
    float hw2 = 0.5f * w2, hh2 = 0.5f * h2;

    // Q center in P frame
    float tx = x2 - x1, ty = y2 - y1;
    float cx = tx * c1 + ty * s1;
    float cy = -tx * s1 + ty * c1;

    // Q half-axes in P frame
    float ux = hw2 * cd, uy = hw2 * sd;
    float vx = -hh2 * sd, vy = hh2 * cd;

    // Q corners in P frame (CCW)
    float e0x = cx - ux, e1x = cx + ux;
    float qx0 = e0x - vx, qx1 = e1x - vx, qx2 = e1x + vx, qx3 = e0x + vx;
    float e0y = cy - uy, e1y = cy + uy;
    float qy0 = e0y - vy, qy1 = e1y - vy, qy2 = e1y + vy, qy3 = e0y + vy;

    // P corners in Q frame
    float Axx = hw1 * cd, Axy = -hw1 * sd;
    float Bxx = hh1 * sd, Byy = hh1 * cd;
    float gx = cx * cd + cy * sd;
    float gy = -cx * sd + cy * cd;
    float f0x = -Axx - gx, f1x = Axx - gx;
    float px0 = f0x - Bxx, px1 = f1x - Bxx, px2 = f1x + Bxx, px3 = f0x + Bxx;
    float f0y = -Axy - gy, f1y = Axy - gy;
    float py0 = f0y - Byy, py1 = f1y - Byy, py2 = f1y + Byy, py3 = f0y + Byy;

    // P edges clipped in Q frame; dirs +-2A, +-2B (rcp shared)
    float rAx = 0.5f * safe_rcp(Axx), rAy = 0.5f * safe_rcp(Axy);
    float rBx = 0.5f * safe_rcp(Bxx), rBy = 0.5f * safe_rcp(Byy);
    float dtP = clip_dt(px0, py0, rAx, rAy, hw2, hh2)
              + clip_dt(px1, py1, rBx, rBy, hw2, hh2)
              + clip_dt(px2, py2, -rAx, -rAy, hw2, hh2)
              + clip_dt(px3, py3, -rBx, -rBy, hw2, hh2);

    // Q edges clipped in P frame (P box IS the AABB)
    float rux = 0.5f * safe_rcp(ux), ruy = 0.5f * safe_rcp(uy);
    float rvx = 0.5f * safe_rcp(vx), rvy = 0.5f * safe_rcp(vy);
    float dq0 = clip_dt(qx0, qy0, rux, ruy, hw1, hh1);
    float dq1 = clip_dt(qx1, qy1, rvx, rvy, hw1, hh1);
    float dq2 = clip_dt(qx2, qy2, -rux, -ruy, hw1, hh1);
    float dq3 = clip_dt(qx3, qy3, -rvx, -rvy, hw1, hh1);
    float dtQ = (dq0 + dq2) + (dq1 + dq3);

    float Ku = 2.0f * (cx * uy - cy * ux);
    float Kv = 2.0f * (cx * vy - cy * vx);
    float A1 = w1 * h1, A2 = w2 * h2;
    float acc = 0.5f * (A1 * dtP + A2 * dtQ)
              + Ku * (dq0 - dq2) + Kv * (dq1 - dq3);
    float area = 0.5f * fabsf(acc);

    float uni = fmaxf((A1 + A2) - area, DEN_EPS_F);
    float iou = area * __builtin_amdgcn_rcpf(uni);
    return -__logf(fmaxf(iou, 1e-6f));
}

#define BOX_PER_THREAD 2

__global__ __launch_bounds__(256, 2) void riou_loss_kernel(
        const float* __restrict__ pred, const float* __restrict__ target,
        float* __restrict__ slots, int n) {
    int t = blockIdx.x * blockDim.x + threadIdx.x;
    int base = t * BOX_PER_THREAD;
    float loss = 0.0f;

    if (base + 1 < n) {
        // 2 boxes x 5 floats = 5 x float2 at byte offset t*40 (8B aligned).
        // Named registers only — no addressable locals anywhere.
        const float2* p2 = reinterpret_cast<const float2*>(pred) + (size_t)t * 5;
        const float2* t2 = reinterpret_cast<const float2*>(target) + (size_t)t * 5;
        float2 pv0 = p2[0], pv1 = p2[1], pv2 = p2[2], pv3 = p2[3], pv4 = p2[4];
        float2 tv0 = t2[0], tv1 = t2[1], tv2 = t2[2], tv3 = t2[3], tv4 = t2[4];
        // box A (index 2t):   {v0.x, v0.y, v1.x, v1.y, v2.x}
        // box B (index 2t+1): {v2.y, v3.x, v3.y, v4.x, v4.y}
        loss  = box_pair_loss(pv0.x, pv0.y, pv1.x, pv1.y, pv2.x,
                              tv0.x, tv0.y, tv1.x, tv1.y, tv2.x);
        loss += box_pair_loss(pv2.y, pv3.x, pv3.y, pv4.x, pv4.y,
                              tv2.y, tv3.x, tv3.y, tv4.x, tv4.y);
    } else if (base < n) {
        // ragged tail (never taken when n % 2 == 0)
        const float* bp = pred + (size_t)base * 5;
        const float* bt = target + (size_t)base * 5;
        loss = box_pair_loss(bp[0], bp[1], bp[2], bp[3], bp[4],
                             bt[0], bt[1], bt[2], bt[3], bt[4]);
    }

    // wave (64-lane) reduction -> LDS across 4 waves -> one plain store
    // per block into its own slot (no atomics, no pre-zero needed).
#pragma unroll
    for (int off = 32; off > 0; off >>= 1)
        loss += __shfl_down(loss, off, 64);

    __shared__ float wsum[4];
    int lane = threadIdx.x & 63;
    int wid = threadIdx.x >> 6;
    if (lane == 0) wsum[wid] = loss;
    __syncthreads();
    if (threadIdx.x == 0)
        slots[blockIdx.x] = (wsum[0] + wsum[1]) + (wsum[2] + wsum[3]);
}

__global__ __launch_bounds__(256) void riou_finish_kernel(
        const float* __restrict__ slots, float* __restrict__ out,
        int nslots, float inv_n) {
    float v = 0.0f;
    for (int j = threadIdx.x; j < nslots; j += 256)
        v += slots[j];
#pragma unroll
    for (int off = 32; off > 0; off >>= 1)
        v += __shfl_down(v, off, 64);

    __shared__ float wsum[4];
    int lane = threadIdx.x & 63;
    int wid = threadIdx.x >> 6;
    if (lane == 0) wsum[wid] = v;
    __syncthreads();
    if (threadIdx.x == 0)
        out[0] = ((wsum[0] + wsum[1]) + (wsum[2] + wsum[3])) * inv_n;
}

extern "C" void kernel_launch(void* const* d_in, const int* in_sizes, int n_in,
                              void* d_out, int out_size, void* d_ws, size_t ws_size,
                              hipStream_t stream) {
    const float* pred = (const float*)d_in[0];
    const float* target = (const float*)d_in[1];
    float* out = (float*)d_out;
    float* slots = (float*)d_ws;
    int n = in_sizes[0] / 5;

    int threads_needed = (n + BOX_PER_THREAD - 1) / BOX_PER_THREAD;
    int block = 256;
    int grid = (threads_needed + block - 1) / block;
    riou_loss_kernel<<<grid, block, 0, stream>>>(pred, target, slots, n);
    riou_finish_kernel<<<1, 256, 0, stream>>>(slots, out, grid,
                                              1.0f / (float)n);
}